// Round 4
// baseline (2143.564 us; speedup 1.0000x reference)
//
#include <hip/hip_runtime.h>
#include <math.h>

#define NS 1024
#define NA 2048
#define CIN 16
#define CC 32
#define LL 150
#define LC 75

typedef __attribute__((ext_vector_type(8))) short short8;
typedef __attribute__((ext_vector_type(4))) float float4v;

__device__ __forceinline__ unsigned short f2bf(float f) {
  // round-to-nearest-even fp32 -> bf16
  unsigned int u = __float_as_uint(f);
  unsigned int r = (u + 0x7FFFu + ((u >> 16) & 1u)) >> 16;
  return (unsigned short)r;
}

// ---------------------------------------------------------------------------
// K1: conv1d(k=5,pad=2) + ReLU + sum over 16 reads, as bf16 MFMA implicit GEMM
// (unchanged — conflict-free b128 staging, 256 threads)
// ---------------------------------------------------------------------------
__global__ __launch_bounds__(256) void k_conv_sum_mfma(const float* __restrict__ x,
                                                       const float* __restrict__ w,
                                                       float* __restrict__ red) {
  __shared__ unsigned short xs[154 * 32];   // 9856 B = 616 slots of 16B
  const int a = blockIdx.x;
  const int tid = threadIdx.x;
  const int lane = tid & 63;
  const int wv = tid >> 6;

  short8 afr[2][3];
  {
    const int mrow = lane & 15;
    const int h = lane >> 4;
    for (int mt = 0; mt < 2; ++mt) {
      const int c = mt * 16 + mrow;
      for (int s = 0; s < 3; ++s) {
        short8 f;
#pragma unroll
        for (int j = 0; j < 8; ++j) {
          int ic = 4 * h + (j >> 1);
          int tap = 2 * s + (j & 1);
          float wval = (tap < 5) ? w[c * 80 + ic * 5 + tap] : 0.f;
          f[j] = (short)f2bf(wval);
        }
        afr[mt][s] = f;
      }
    }
  }

  float4v sum[2][3];
#pragma unroll
  for (int mt = 0; mt < 2; ++mt)
#pragma unroll
    for (int nt = 0; nt < 3; ++nt) sum[mt][nt] = (float4v)(0.f);

  const int nbase = wv * 48;
  const int nrow = lane & 15;
  const int hh = lane >> 4;
  const float4v zf = (float4v)(0.f);

  for (int r = 0; r < 16; ++r) {
    __syncthreads();
    const float* xr = x + (size_t)(a * 16 + r) * (CIN * LL);
    for (int s = tid; s < 616; s += 256) {
      const int p = s >> 2;
      const int h4 = (s & 3) * 4;
      const float* xb = xr + h4 * LL + p;
      const bool qe_ok = (p >= 2) && (p <= 151);
      const bool qo_ok = (p >= 1) && (p <= 150);
      short8 f;
#pragma unroll
      for (int c = 0; c < 4; ++c) {
        float ve = qe_ok ? xb[c * LL - 2] : 0.f;
        float vo = qo_ok ? xb[c * LL - 1] : 0.f;
        f[2 * c]     = (short)f2bf(ve);
        f[2 * c + 1] = (short)f2bf(vo);
      }
      *(short8*)&xs[s * 8] = f;
    }
    __syncthreads();

    float4v acc[2][3];
#pragma unroll
    for (int s = 0; s < 3; ++s) {
#pragma unroll
      for (int nt = 0; nt < 3; ++nt) {
        int p = nbase + nt * 16 + nrow + 2 * s;
        if (p >= 154) p -= 154;
        short8 bfrag = *(const short8*)&xs[(4 * p + hh) * 8];
#pragma unroll
        for (int mt = 0; mt < 2; ++mt) {
          acc[mt][nt] = __builtin_amdgcn_mfma_f32_16x16x32_bf16(
              afr[mt][s], bfrag, (s == 0) ? zf : acc[mt][nt], 0, 0, 0);
        }
      }
    }
#pragma unroll
    for (int mt = 0; mt < 2; ++mt)
#pragma unroll
      for (int nt = 0; nt < 3; ++nt)
#pragma unroll
        for (int q = 0; q < 4; ++q) sum[mt][nt][q] += fmaxf(acc[mt][nt][q], 0.f);
  }

  const int ccol = lane & 15;
  const int crow4 = (lane >> 4) * 4;
  for (int mt = 0; mt < 2; ++mt)
    for (int nt = 0; nt < 3; ++nt) {
      int l = nbase + nt * 16 + ccol;
      if (l < LL) {
#pragma unroll
        for (int q = 0; q < 4; ++q) {
          int c = mt * 16 + crow4 + q;
          red[(size_t)a * (CC * LL) + c * LL + l] = sum[mt][nt][q];
        }
      }
    }
}

// ---------------------------------------------------------------------------
// K2: red2 = relu(comb_w @ [red0|red1]) in place over red0 (unchanged)
// ---------------------------------------------------------------------------
__global__ __launch_bounds__(256) void k_comb(const float* __restrict__ red0,
                                              const float* __restrict__ red1,
                                              const float* __restrict__ cw,
                                              float* __restrict__ out) {
  __shared__ float ins[64][152];
  __shared__ float cwl[64][CC];
  const int a = blockIdx.x;
  const int tid = threadIdx.x;

  for (int i = tid; i < 64 * CC; i += 256) {
    int c = i & 31; int c2 = i >> 5;
    cwl[c2][c] = cw[c * 64 + c2];
  }
  for (int i = tid; i < CC * LL; i += 256) {
    int c2 = i / LL; int l = i - c2 * LL;
    ins[c2][l] = red0[(size_t)a * (CC * LL) + i];
    ins[32 + c2][l] = red1[(size_t)a * (CC * LL) + i];
  }
  __syncthreads();

  const int c = tid & 31;
  const int lg = tid >> 5;
  const int l0 = lg * 19;
  const int nl = (LL - l0 < 19) ? (LL - l0) : 19;
  float v[19];
#pragma unroll
  for (int j = 0; j < 19; ++j) v[j] = 0.f;
  for (int c2 = 0; c2 < 64; ++c2) {
    float wv = cwl[c2][c];
#pragma unroll
    for (int j = 0; j < 19; ++j) v[j] += wv * ins[c2][l0 + j];
  }
  float* o = out + (size_t)a * (CC * LL) + c * LL + l0;
  for (int j = 0; j < nl; ++j) o[j] = fmaxf(v[j], 0.f);
}

// ---------------------------------------------------------------------------
// K3: compressor conv (k=3, dil=2, stride=2, pad=2) + ReLU (unchanged)
// ---------------------------------------------------------------------------
__global__ __launch_bounds__(256) void k_compress(const float* __restrict__ src,
                                                  const float* __restrict__ w,
                                                  float* __restrict__ dst,
                                                  int site_mode) {
  __shared__ float ins[CC][164];
  __shared__ float ws[CC][3][CC];
  const int n = blockIdx.x;
  const int tid = threadIdx.x;

  for (int i = tid; i < CC * 3 * CC; i += 256) {
    int c = i & 31; int kk = i >> 5; int ic = kk / 3; int t = kk - ic * 3;
    ws[ic][t][c] = w[c * (CC * 3) + ic * 3 + t];
  }
  if (tid < CC) { ins[tid][0] = 0.f; ins[tid][1] = 0.f; ins[tid][152] = 0.f; ins[tid][153] = 0.f; }

  if (site_mode) {
    const float* s0 = src + (size_t)(2 * n) * (CC * LL);
    const float* s1 = src + (size_t)(2 * n + 1) * (CC * LL);
    for (int i = tid; i < CC * LL; i += 256) {
      int ic = i / LL; int l = i - ic * LL;
      ins[ic][l + 2] = s0[i] + s1[i];
    }
  } else {
    const float* s0 = src + (size_t)n * (CC * LL);
    for (int i = tid; i < CC * LL; i += 256) {
      int ic = i / LL; int l = i - ic * LL;
      ins[ic][l + 2] = s0[i];
    }
  }
  __syncthreads();

  const int c = tid & 31;
  const int jg = tid >> 5;
  const int j0 = jg * 10;
  const int nj = (LC - j0 < 10) ? (LC - j0) : 10;
  float v[10];
#pragma unroll
  for (int j = 0; j < 10; ++j) v[j] = 0.f;
  for (int ic = 0; ic < CC; ++ic) {
    float w0 = ws[ic][0][c], w1 = ws[ic][1][c], w2 = ws[ic][2][c];
    float xw[12];
#pragma unroll
    for (int i = 0; i < 12; ++i) xw[i] = ins[ic][2 * j0 + 2 * i];
#pragma unroll
    for (int j = 0; j < 10; ++j) v[j] += w0 * xw[j] + w1 * xw[j + 1] + w2 * xw[j + 2];
  }
  float* o = dst + (size_t)n * (CC * LC) + c * LC + j0;
  for (int j = 0; j < nj; ++j) o[j] = fmaxf(v[j], 0.f);
}

// ---------------------------------------------------------------------------
// K4 v4b: per-ALLELE fused cross-attention, register-lean.
// FIX vs v3-round submission: B2 projection loop decomposes idx as
// (o = idx & 31 == lane t, m = idx >> 5) so the per-lane weight columns
// wkc/wvc (indexed by t) match the output channel o. The round-3 failure
// used o = idx/150 with t-indexed weights -> wrong channel mixing.
//
// Arena (floats), 81280 B total -> 2 blocks/CU:
//  KV   @0      [32][150] = 4800   (dead after B2)
//  W    @4800   wq/wk/wv [32][33]  = 3168 (end 7968; wq dead after B1)
//  QT   @8064   [75][32]  = 2400   (end 10464)
//  CF   @10464  [32][77]  = 2464   (dead after B1)
//  KB   @10464  [32][152] = 4864   (alias CF; end 15328)
//  VB   @15328  [32][156] = 4992   (end 20320)
//  ROWP @0      [8][5][152] = 6080 (phase D alias over KV+wq+part of wk, all dead)
//  PART @6080 [8][32], MS @6336 [32]
// ---------------------------------------------------------------------------
#define BKV   0
#define BW    4800
#define BQT   8064
#define BCF   10464
#define BKB   10464
#define BVB   15328
#define BROWP 0
#define BPART 6080
#define BMS   6336
#define ARENA 20320

__global__ __launch_bounds__(256, 2) void k_attn(const float* __restrict__ cfa,
                                                 const float* __restrict__ cfs0,
                                                 const float* __restrict__ wq,
                                                 const float* __restrict__ wk,
                                                 const float* __restrict__ wv,
                                                 const float* __restrict__ wo,
                                                 float* __restrict__ eout) {
  __shared__ float ar[ARENA];
  const int a = blockIdx.x;
  const int s = a >> 1;
  const int tid = threadIdx.x;
  const int g = tid >> 5;
  const int t = tid & 31;

  // ---- phase A: stage weights (in-major, stride 33), kv, cf ----
  for (int i = tid; i < CC * CC; i += 256) {
    int o = i >> 5, ii = i & 31;
    ar[BW + ii * 33 + o]        = wq[i];
    ar[BW + 1056 + ii * 33 + o] = wk[i];
    ar[BW + 2112 + ii * 33 + o] = wv[i];
  }
  {
    const float* sg = cfs0 + (size_t)s * (CC * LC);
    const float* a0 = cfa + (size_t)(2 * s) * (CC * LC);
    const float* a1 = a0 + CC * LC;
    const int sel = a & 1;
    for (int i = tid; i < CC * LC; i += 256) {
      int c = i / 75, l = i - c * 75;
      float v0 = a0[i], v1 = a1[i];
      ar[BKV + c * 150 + l]      = sg[i];
      ar[BKV + c * 150 + 75 + l] = v0 + v1;
      ar[BCF + c * 77 + l]       = sel ? v1 : v0;
    }
  }
  __syncthreads();

  // ---- phase B1: q -> QT (LDS), cf partial column-sum ----
  float cfp = 0.f;
  {
    float wqc[32];
#pragma unroll
    for (int ii = 0; ii < 32; ++ii) wqc[ii] = ar[BW + ii * 33 + t];
    for (int row = g; row < 75; row += 8) {
      float acc = 0.f;
#pragma unroll
      for (int ii = 0; ii < 32; ++ii) acc += wqc[ii] * ar[BCF + ii * 77 + row];
      ar[BQT + row * 32 + t] = acc;
      cfp += ar[BCF + t * 77 + row];
    }
  }
  __syncthreads();   // QT visible; CF reads done -> KB may overwrite

  // ---- phase B2: k,v projection -> KB (over CF), VB ----
  // o = idx & 31 == t (256 stride preserves low 5 bits), so the t-indexed
  // weight registers produce channel t's outputs. m = idx >> 5 covers 0..149.
  {
    float wkc[32], wvc[32];
#pragma unroll
    for (int ii = 0; ii < 32; ++ii) {
      wkc[ii] = ar[BW + 1056 + ii * 33 + t];
      wvc[ii] = ar[BW + 2112 + ii * 33 + t];
    }
    for (int idx = tid; idx < CC * LL; idx += 256) {
      int o = idx & 31, m = idx >> 5;
      float ka = 0.f, va = 0.f;
#pragma unroll
      for (int ii = 0; ii < 32; ++ii) {
        float x = ar[BKV + ii * 150 + m];
        ka += wkc[ii] * x;
        va += wvc[ii] * x;
      }
      ar[BKB + o * 152 + m] = ka;
      ar[BVB + o * 156 + m] = va;
    }
    if (tid < 64) ar[BVB + (tid >> 1) * 156 + 150 + (tid & 1)] = 0.f;  // PV pad
  }
  __syncthreads();   // KB/VB ready; KV+W dead -> ROWP may overwrite

  // ---- phase D: per-chunk (5 rows) scores -> softmax -> PV ----
  float ms = 0.f;
  const int rbase = BROWP + g * 760;
  const float scale = 0.17677669529663687f;   // 1/sqrt(32)
#pragma unroll 1
  for (int cc = 0; cc < 2; ++cc) {
    const int ch = g + 8 * cc;
    if (ch >= 15) break;
    const int r0 = ch * 5;

    float2 acc[5][3];
#pragma unroll
    for (int i = 0; i < 5; ++i)
#pragma unroll
      for (int u = 0; u < 3; ++u) acc[i][u] = make_float2(0.f, 0.f);

    for (int c4 = 0; c4 < 32; c4 += 4) {
      float4 qv[5];
#pragma unroll
      for (int i = 0; i < 5; ++i) qv[i] = *(const float4*)&ar[BQT + (r0 + i) * 32 + c4];
#pragma unroll
      for (int cj = 0; cj < 4; ++cj) {
        const int cb = BKB + (c4 + cj) * 152 + 2 * t;
        float2 k0 = *(const float2*)&ar[cb];
        float2 k1 = *(const float2*)&ar[cb + 64];
        float2 k2 = *(const float2*)&ar[cb + 128];
#pragma unroll
        for (int i = 0; i < 5; ++i) {
          float q = (cj == 0) ? qv[i].x : (cj == 1) ? qv[i].y : (cj == 2) ? qv[i].z : qv[i].w;
          acc[i][0].x += q * k0.x; acc[i][0].y += q * k0.y;
          acc[i][1].x += q * k1.x; acc[i][1].y += q * k1.y;
          acc[i][2].x += q * k2.x; acc[i][2].y += q * k2.y;
        }
      }
    }

    float inv[5];
#pragma unroll
    for (int i = 0; i < 5; ++i) {
      float s0x = acc[i][0].x * scale, s0y = acc[i][0].y * scale;
      float s1x = acc[i][1].x * scale, s1y = acc[i][1].y * scale;
      float s2x = acc[i][2].x * scale, s2y = acc[i][2].y * scale;
      if (t >= 11) { s2x = -1e30f; s2y = -1e30f; }   // m=128+2t >= 150
      float mx = fmaxf(fmaxf(fmaxf(s0x, s0y), fmaxf(s1x, s1y)), fmaxf(s2x, s2y));
#pragma unroll
      for (int off = 16; off > 0; off >>= 1) mx = fmaxf(mx, __shfl_xor(mx, off, 32));
      float p0x = __expf(s0x - mx), p0y = __expf(s0y - mx);
      float p1x = __expf(s1x - mx), p1y = __expf(s1y - mx);
      float p2x = __expf(s2x - mx), p2y = __expf(s2y - mx);
      float ss = p0x + p0y + p1x + p1y + p2x + p2y;
#pragma unroll
      for (int off = 16; off > 0; off >>= 1) ss += __shfl_xor(ss, off, 32);
      inv[i] = 1.f / ss;
      const int rb = rbase + i * 152 + 2 * t;
      *(float2*)&ar[rb]      = make_float2(p0x, p0y);
      *(float2*)&ar[rb + 64] = make_float2(p1x, p1y);
      if (t <= 11) *(float2*)&ar[rb + 128] = make_float2(p2x, p2y);  // t=11 writes 0s at m=150,151
    }

    float pv[5] = {0.f, 0.f, 0.f, 0.f, 0.f};
    for (int mq = 0; mq < 38; ++mq) {
      float4 vv = *(const float4*)&ar[BVB + t * 156 + 4 * mq];
#pragma unroll
      for (int i = 0; i < 5; ++i) {
        float4 pp = *(const float4*)&ar[rbase + i * 152 + 4 * mq];
        pv[i] += pp.x * vv.x + pp.y * vv.y + pp.z * vv.z + pp.w * vv.w;
      }
    }
#pragma unroll
    for (int i = 0; i < 5; ++i) ms += pv[i] * inv[i];
  }

  ar[BPART + g * 32 + t] = cfp + ms;
  __syncthreads();

  // ---- epilogue: mean over l, project with wo ----
  if (tid < 32) {
    float tot = 0.f;
#pragma unroll
    for (int gg = 0; gg < 8; ++gg) tot += ar[BPART + gg * 32 + tid];
    ar[BMS + tid] = tot * (1.f / 75.f);
  }
  __syncthreads();
  if (tid < 2) {
    float e = 0.f;
#pragma unroll
    for (int c2 = 0; c2 < CC; ++c2) e += wo[tid * CC + c2] * ar[BMS + c2];
    eout[a * 2 + tid] = e;
  }
}

// ---------------------------------------------------------------------------
// K5: meta head per site (unchanged)
// ---------------------------------------------------------------------------
__global__ __launch_bounds__(64) void k_meta(const float* __restrict__ cfs0,
                                             const float* __restrict__ cfa2,
                                             const float* __restrict__ mw,
                                             const float* __restrict__ mb,
                                             float* __restrict__ mout) {
  __shared__ float feat[64];
  __shared__ float lgt[3];
  const int s = blockIdx.x;
  const int tid = threadIdx.x;
  float f = 0.f;
  if (tid < 32) {
    const float* p = cfs0 + (size_t)s * (CC * LC) + tid * LC;
    for (int l = 0; l < LC; ++l) f += p[l];
  } else {
    const float* p0 = cfa2 + (size_t)(2 * s) * (CC * LC) + (tid - 32) * LC;
    const float* p1 = cfa2 + (size_t)(2 * s + 1) * (CC * LC) + (tid - 32) * LC;
    for (int l = 0; l < LC; ++l) f += p0[l] + p1[l];
  }
  feat[tid] = f * (1.f / 75.f);
  __syncthreads();
  if (tid < 3) {
    float acc2 = mb[tid];
    for (int c2 = 0; c2 < 64; ++c2) acc2 += mw[tid * 64 + c2] * feat[c2];
    lgt[tid] = acc2;
  }
  __syncthreads();
  if (tid < 3) {
    float mx = fmaxf(lgt[0], fmaxf(lgt[1], lgt[2]));
    float e0 = __expf(lgt[0] - mx), e1 = __expf(lgt[1] - mx), e2 = __expf(lgt[2] - mx);
    mout[s * 3 + tid] = __expf(lgt[tid] - mx) / (e0 + e1 + e2);
  }
}

// ---------------------------------------------------------------------------
extern "C" void kernel_launch(void* const* d_in, const int* in_sizes, int n_in,
                              void* d_out, int out_size, void* d_ws, size_t ws_size,
                              hipStream_t stream) {
  const float* t0      = (const float*)d_in[0];
  const float* t1      = (const float*)d_in[1];
  const float* conv0_w = (const float*)d_in[2];
  const float* conv1_w = (const float*)d_in[3];
  const float* comp0_w = (const float*)d_in[4];
  const float* comp1_w = (const float*)d_in[5];
  const float* comp2_w = (const float*)d_in[6];
  const float* xq0 = (const float*)d_in[7];
  const float* xk0 = (const float*)d_in[8];
  const float* xv0 = (const float*)d_in[9];
  const float* xo0 = (const float*)d_in[10];
  const float* xq1 = (const float*)d_in[11];
  const float* xk1 = (const float*)d_in[12];
  const float* xv1 = (const float*)d_in[13];
  const float* xo1 = (const float*)d_in[14];
  const float* xq2 = (const float*)d_in[15];
  const float* xk2 = (const float*)d_in[16];
  const float* xv2 = (const float*)d_in[17];
  const float* xo2 = (const float*)d_in[18];
  const float* comb_w = (const float*)d_in[19];
  const float* meta_w = (const float*)d_in[20];
  const float* meta_b = (const float*)d_in[21];

  float* wsf  = (float*)d_ws;
  float* red0 = wsf;
  float* red1 = red0 + (size_t)NA * CC * LL;
  float* cfa  = red1 + (size_t)NA * CC * LL;
  float* cfs0 = cfa + (size_t)NA * CC * LC;
  float* out  = (float*)d_out;

  k_conv_sum_mfma<<<NA, 256, 0, stream>>>(t0, conv0_w, red0);
  k_conv_sum_mfma<<<NA, 256, 0, stream>>>(t1, conv1_w, red1);

  k_compress<<<NA, 256, 0, stream>>>(red0, comp0_w, cfa, 0);
  k_compress<<<NS, 256, 0, stream>>>(red0, comp0_w, cfs0, 1);
  k_attn<<<NA, 256, 0, stream>>>(cfa, cfs0, xq0, xk0, xv0, xo0, out + 0);

  k_compress<<<NA, 256, 0, stream>>>(red1, comp1_w, cfa, 0);
  k_compress<<<NS, 256, 0, stream>>>(red1, comp1_w, cfs0, 1);
  k_attn<<<NA, 256, 0, stream>>>(cfa, cfs0, xq1, xk1, xv1, xo1, out + 2 * NA);

  k_comb<<<NA, 256, 0, stream>>>(red0, red1, comb_w, red0);
  k_compress<<<NA, 256, 0, stream>>>(red0, comp2_w, cfa, 0);
  k_compress<<<NS, 256, 0, stream>>>(red0, comp2_w, cfs0, 1);
  k_attn<<<NA, 256, 0, stream>>>(cfa, cfs0, xq2, xk2, xv2, xo2, out + 4 * NA);

  k_meta<<<NS, 64, 0, stream>>>(cfs0, cfa, meta_w, meta_b, out + 6 * NA);
}

// Round 5
// 1570.276 us; speedup vs baseline: 1.3651x; 1.3651x over previous
//
#include <hip/hip_runtime.h>
#include <math.h>

#define NS 1024
#define NA 2048
#define CIN 16
#define CC 32
#define LL 150
#define LC 75

typedef __attribute__((ext_vector_type(8))) short short8;
typedef __attribute__((ext_vector_type(4))) float float4v;

__device__ __forceinline__ unsigned short f2bf(float f) {
  // round-to-nearest-even fp32 -> bf16
  unsigned int u = __float_as_uint(f);
  unsigned int r = (u + 0x7FFFu + ((u >> 16) & 1u)) >> 16;
  return (unsigned short)r;
}

// ---------------------------------------------------------------------------
// K1: conv1d(k=5,pad=2) + ReLU + sum over 16 reads, as bf16 MFMA implicit GEMM
// (unchanged — conflict-free b128 staging, 256 threads)
// ---------------------------------------------------------------------------
__global__ __launch_bounds__(256) void k_conv_sum_mfma(const float* __restrict__ x,
                                                       const float* __restrict__ w,
                                                       float* __restrict__ red) {
  __shared__ unsigned short xs[154 * 32];   // 9856 B = 616 slots of 16B
  const int a = blockIdx.x;
  const int tid = threadIdx.x;
  const int lane = tid & 63;
  const int wv = tid >> 6;

  short8 afr[2][3];
  {
    const int mrow = lane & 15;
    const int h = lane >> 4;
    for (int mt = 0; mt < 2; ++mt) {
      const int c = mt * 16 + mrow;
      for (int s = 0; s < 3; ++s) {
        short8 f;
#pragma unroll
        for (int j = 0; j < 8; ++j) {
          int ic = 4 * h + (j >> 1);
          int tap = 2 * s + (j & 1);
          float wval = (tap < 5) ? w[c * 80 + ic * 5 + tap] : 0.f;
          f[j] = (short)f2bf(wval);
        }
        afr[mt][s] = f;
      }
    }
  }

  float4v sum[2][3];
#pragma unroll
  for (int mt = 0; mt < 2; ++mt)
#pragma unroll
    for (int nt = 0; nt < 3; ++nt) sum[mt][nt] = (float4v)(0.f);

  const int nbase = wv * 48;
  const int nrow = lane & 15;
  const int hh = lane >> 4;
  const float4v zf = (float4v)(0.f);

  for (int r = 0; r < 16; ++r) {
    __syncthreads();
    const float* xr = x + (size_t)(a * 16 + r) * (CIN * LL);
    for (int s = tid; s < 616; s += 256) {
      const int p = s >> 2;
      const int h4 = (s & 3) * 4;
      const float* xb = xr + h4 * LL + p;
      const bool qe_ok = (p >= 2) && (p <= 151);
      const bool qo_ok = (p >= 1) && (p <= 150);
      short8 f;
#pragma unroll
      for (int c = 0; c < 4; ++c) {
        float ve = qe_ok ? xb[c * LL - 2] : 0.f;
        float vo = qo_ok ? xb[c * LL - 1] : 0.f;
        f[2 * c]     = (short)f2bf(ve);
        f[2 * c + 1] = (short)f2bf(vo);
      }
      *(short8*)&xs[s * 8] = f;
    }
    __syncthreads();

    float4v acc[2][3];
#pragma unroll
    for (int s = 0; s < 3; ++s) {
#pragma unroll
      for (int nt = 0; nt < 3; ++nt) {
        int p = nbase + nt * 16 + nrow + 2 * s;
        if (p >= 154) p -= 154;
        short8 bfrag = *(const short8*)&xs[(4 * p + hh) * 8];
#pragma unroll
        for (int mt = 0; mt < 2; ++mt) {
          acc[mt][nt] = __builtin_amdgcn_mfma_f32_16x16x32_bf16(
              afr[mt][s], bfrag, (s == 0) ? zf : acc[mt][nt], 0, 0, 0);
        }
      }
    }
#pragma unroll
    for (int mt = 0; mt < 2; ++mt)
#pragma unroll
      for (int nt = 0; nt < 3; ++nt)
#pragma unroll
        for (int q = 0; q < 4; ++q) sum[mt][nt][q] += fmaxf(acc[mt][nt][q], 0.f);
  }

  const int ccol = lane & 15;
  const int crow4 = (lane >> 4) * 4;
  for (int mt = 0; mt < 2; ++mt)
    for (int nt = 0; nt < 3; ++nt) {
      int l = nbase + nt * 16 + ccol;
      if (l < LL) {
#pragma unroll
        for (int q = 0; q < 4; ++q) {
          int c = mt * 16 + crow4 + q;
          red[(size_t)a * (CC * LL) + c * LL + l] = sum[mt][nt][q];
        }
      }
    }
}

// ---------------------------------------------------------------------------
// K2: red2 = relu(comb_w @ [red0|red1]) in place over red0 (unchanged)
// ---------------------------------------------------------------------------
__global__ __launch_bounds__(256) void k_comb(const float* __restrict__ red0,
                                              const float* __restrict__ red1,
                                              const float* __restrict__ cw,
                                              float* __restrict__ out) {
  __shared__ float ins[64][152];
  __shared__ float cwl[64][CC];
  const int a = blockIdx.x;
  const int tid = threadIdx.x;

  for (int i = tid; i < 64 * CC; i += 256) {
    int c = i & 31; int c2 = i >> 5;
    cwl[c2][c] = cw[c * 64 + c2];
  }
  for (int i = tid; i < CC * LL; i += 256) {
    int c2 = i / LL; int l = i - c2 * LL;
    ins[c2][l] = red0[(size_t)a * (CC * LL) + i];
    ins[32 + c2][l] = red1[(size_t)a * (CC * LL) + i];
  }
  __syncthreads();

  const int c = tid & 31;
  const int lg = tid >> 5;
  const int l0 = lg * 19;
  const int nl = (LL - l0 < 19) ? (LL - l0) : 19;
  float v[19];
#pragma unroll
  for (int j = 0; j < 19; ++j) v[j] = 0.f;
  for (int c2 = 0; c2 < 64; ++c2) {
    float wv = cwl[c2][c];
#pragma unroll
    for (int j = 0; j < 19; ++j) v[j] += wv * ins[c2][l0 + j];
  }
  float* o = out + (size_t)a * (CC * LL) + c * LL + l0;
  for (int j = 0; j < nl; ++j) o[j] = fmaxf(v[j], 0.f);
}

// ---------------------------------------------------------------------------
// K3: compressor conv (k=3, dil=2, stride=2, pad=2) + ReLU (unchanged)
// ---------------------------------------------------------------------------
__global__ __launch_bounds__(256) void k_compress(const float* __restrict__ src,
                                                  const float* __restrict__ w,
                                                  float* __restrict__ dst,
                                                  int site_mode) {
  __shared__ float ins[CC][164];
  __shared__ float ws[CC][3][CC];
  const int n = blockIdx.x;
  const int tid = threadIdx.x;

  for (int i = tid; i < CC * 3 * CC; i += 256) {
    int c = i & 31; int kk = i >> 5; int ic = kk / 3; int t = kk - ic * 3;
    ws[ic][t][c] = w[c * (CC * 3) + ic * 3 + t];
  }
  if (tid < CC) { ins[tid][0] = 0.f; ins[tid][1] = 0.f; ins[tid][152] = 0.f; ins[tid][153] = 0.f; }

  if (site_mode) {
    const float* s0 = src + (size_t)(2 * n) * (CC * LL);
    const float* s1 = src + (size_t)(2 * n + 1) * (CC * LL);
    for (int i = tid; i < CC * LL; i += 256) {
      int ic = i / LL; int l = i - ic * LL;
      ins[ic][l + 2] = s0[i] + s1[i];
    }
  } else {
    const float* s0 = src + (size_t)n * (CC * LL);
    for (int i = tid; i < CC * LL; i += 256) {
      int ic = i / LL; int l = i - ic * LL;
      ins[ic][l + 2] = s0[i];
    }
  }
  __syncthreads();

  const int c = tid & 31;
  const int jg = tid >> 5;
  const int j0 = jg * 10;
  const int nj = (LC - j0 < 10) ? (LC - j0) : 10;
  float v[10];
#pragma unroll
  for (int j = 0; j < 10; ++j) v[j] = 0.f;
  for (int ic = 0; ic < CC; ++ic) {
    float w0 = ws[ic][0][c], w1 = ws[ic][1][c], w2 = ws[ic][2][c];
    float xw[12];
#pragma unroll
    for (int i = 0; i < 12; ++i) xw[i] = ins[ic][2 * j0 + 2 * i];
#pragma unroll
    for (int j = 0; j < 10; ++j) v[j] += w0 * xw[j] + w1 * xw[j + 1] + w2 * xw[j + 2];
  }
  float* o = dst + (size_t)n * (CC * LC) + c * LC + j0;
  for (int j = 0; j < nj; ++j) o[j] = fmaxf(v[j], 0.f);
}

// ---------------------------------------------------------------------------
// K4 v5: per-ALLELE fused cross-attention, spill-free.
// vs v4b: (1) plain __launch_bounds__(256) — the ",2" min-waves hint made the
// compiler clamp VGPRs to 128 and spill the phase-D tile (439 MB/dispatch of
// scratch writes, HBM-bound at 2.3 TB/s); (2) score loop steps 2 channels at
// a time with float2 q loads -> peak live state ~70 regs, fits any budget.
//
// Arena (floats), 81280 B total -> 2 blocks/CU:
//  KV   @0      [32][150] = 4800   (dead after B2)
//  W    @4800   wq/wk/wv [32][33]  = 3168 (end 7968; wq dead after B1)
//  QT   @8064   [75][32]  = 2400   (end 10464)
//  CF   @10464  [32][77]  = 2464   (dead after B1)
//  KB   @10464  [32][152] = 4864   (alias CF; end 15328)
//  VB   @15328  [32][156] = 4992   (end 20320)
//  ROWP @0      [8][5][152] = 6080 (phase D alias over KV+wq, dead)
//  PART @6080 [8][32], MS @6336 [32]
// ---------------------------------------------------------------------------
#define BKV   0
#define BW    4800
#define BQT   8064
#define BCF   10464
#define BKB   10464
#define BVB   15328
#define BROWP 0
#define BPART 6080
#define BMS   6336
#define ARENA 20320

__global__ __launch_bounds__(256) void k_attn(const float* __restrict__ cfa,
                                              const float* __restrict__ cfs0,
                                              const float* __restrict__ wq,
                                              const float* __restrict__ wk,
                                              const float* __restrict__ wv,
                                              const float* __restrict__ wo,
                                              float* __restrict__ eout) {
  __shared__ float ar[ARENA];
  const int a = blockIdx.x;
  const int s = a >> 1;
  const int tid = threadIdx.x;
  const int g = tid >> 5;
  const int t = tid & 31;

  // ---- phase A: stage weights (in-major, stride 33), kv, cf ----
  for (int i = tid; i < CC * CC; i += 256) {
    int o = i >> 5, ii = i & 31;
    ar[BW + ii * 33 + o]        = wq[i];
    ar[BW + 1056 + ii * 33 + o] = wk[i];
    ar[BW + 2112 + ii * 33 + o] = wv[i];
  }
  {
    const float* sg = cfs0 + (size_t)s * (CC * LC);
    const float* a0 = cfa + (size_t)(2 * s) * (CC * LC);
    const float* a1 = a0 + CC * LC;
    const int sel = a & 1;
    for (int i = tid; i < CC * LC; i += 256) {
      int c = i / 75, l = i - c * 75;
      float v0 = a0[i], v1 = a1[i];
      ar[BKV + c * 150 + l]      = sg[i];
      ar[BKV + c * 150 + 75 + l] = v0 + v1;
      ar[BCF + c * 77 + l]       = sel ? v1 : v0;
    }
  }
  __syncthreads();

  // ---- phase B1: q -> QT (LDS), cf partial column-sum ----
  float cfp = 0.f;
  {
    float wqc[32];
#pragma unroll
    for (int ii = 0; ii < 32; ++ii) wqc[ii] = ar[BW + ii * 33 + t];
    for (int row = g; row < 75; row += 8) {
      float acc = 0.f;
#pragma unroll
      for (int ii = 0; ii < 32; ++ii) acc += wqc[ii] * ar[BCF + ii * 77 + row];
      ar[BQT + row * 32 + t] = acc;
      cfp += ar[BCF + t * 77 + row];
    }
  }
  __syncthreads();   // QT visible; CF reads done -> KB may overwrite

  // ---- phase B2: k,v projection -> KB (over CF), VB ----
  // o = idx & 31 == t (256 stride preserves low 5 bits), so the t-indexed
  // weight registers produce channel t's outputs. m = idx >> 5 covers 0..149.
  {
    float wkc[32], wvc[32];
#pragma unroll
    for (int ii = 0; ii < 32; ++ii) {
      wkc[ii] = ar[BW + 1056 + ii * 33 + t];
      wvc[ii] = ar[BW + 2112 + ii * 33 + t];
    }
    for (int idx = tid; idx < CC * LL; idx += 256) {
      int o = idx & 31, m = idx >> 5;
      float ka = 0.f, va = 0.f;
#pragma unroll
      for (int ii = 0; ii < 32; ++ii) {
        float x = ar[BKV + ii * 150 + m];
        ka += wkc[ii] * x;
        va += wvc[ii] * x;
      }
      ar[BKB + o * 152 + m] = ka;
      ar[BVB + o * 156 + m] = va;
    }
    if (tid < 64) ar[BVB + (tid >> 1) * 156 + 150 + (tid & 1)] = 0.f;  // PV pad
  }
  __syncthreads();   // KB/VB ready; KV+W dead -> ROWP may overwrite

  // ---- phase D: per-chunk (5 rows) scores -> softmax -> PV ----
  float ms = 0.f;
  const int rbase = BROWP + g * 760;
  const float scale = 0.17677669529663687f;   // 1/sqrt(32)
#pragma unroll 1
  for (int cc = 0; cc < 2; ++cc) {
    const int ch = g + 8 * cc;
    if (ch >= 15) break;
    const int r0 = ch * 5;

    float2 acc[5][3];
#pragma unroll
    for (int i = 0; i < 5; ++i)
#pragma unroll
      for (int u = 0; u < 3; ++u) acc[i][u] = make_float2(0.f, 0.f);

    // 2 channels per step: q as float2 (broadcast reads), k as 6 float2s.
    // Peak live ~52 regs (acc 30 + q 10 + k 12).
#pragma unroll 1
    for (int c2 = 0; c2 < 32; c2 += 2) {
      float2 q01[5];
#pragma unroll
      for (int i = 0; i < 5; ++i) q01[i] = *(const float2*)&ar[BQT + (r0 + i) * 32 + c2];
      const int cb0 = BKB + c2 * 152 + 2 * t;
      const int cb1 = cb0 + 152;
      float2 ka0 = *(const float2*)&ar[cb0];
      float2 ka1 = *(const float2*)&ar[cb0 + 64];
      float2 ka2 = *(const float2*)&ar[cb0 + 128];
      float2 kb0 = *(const float2*)&ar[cb1];
      float2 kb1 = *(const float2*)&ar[cb1 + 64];
      float2 kb2 = *(const float2*)&ar[cb1 + 128];
#pragma unroll
      for (int i = 0; i < 5; ++i) {
        acc[i][0].x += q01[i].x * ka0.x + q01[i].y * kb0.x;
        acc[i][0].y += q01[i].x * ka0.y + q01[i].y * kb0.y;
        acc[i][1].x += q01[i].x * ka1.x + q01[i].y * kb1.x;
        acc[i][1].y += q01[i].x * ka1.y + q01[i].y * kb1.y;
        acc[i][2].x += q01[i].x * ka2.x + q01[i].y * kb2.x;
        acc[i][2].y += q01[i].x * ka2.y + q01[i].y * kb2.y;
      }
    }

    float inv[5];
#pragma unroll
    for (int i = 0; i < 5; ++i) {
      float s0x = acc[i][0].x * scale, s0y = acc[i][0].y * scale;
      float s1x = acc[i][1].x * scale, s1y = acc[i][1].y * scale;
      float s2x = acc[i][2].x * scale, s2y = acc[i][2].y * scale;
      if (t >= 11) { s2x = -1e30f; s2y = -1e30f; }   // m=128+2t >= 150
      float mx = fmaxf(fmaxf(fmaxf(s0x, s0y), fmaxf(s1x, s1y)), fmaxf(s2x, s2y));
#pragma unroll
      for (int off = 16; off > 0; off >>= 1) mx = fmaxf(mx, __shfl_xor(mx, off, 32));
      float p0x = __expf(s0x - mx), p0y = __expf(s0y - mx);
      float p1x = __expf(s1x - mx), p1y = __expf(s1y - mx);
      float p2x = __expf(s2x - mx), p2y = __expf(s2y - mx);
      float ss = p0x + p0y + p1x + p1y + p2x + p2y;
#pragma unroll
      for (int off = 16; off > 0; off >>= 1) ss += __shfl_xor(ss, off, 32);
      inv[i] = 1.f / ss;
      const int rb = rbase + i * 152 + 2 * t;
      *(float2*)&ar[rb]      = make_float2(p0x, p0y);
      *(float2*)&ar[rb + 64] = make_float2(p1x, p1y);
      if (t <= 11) *(float2*)&ar[rb + 128] = make_float2(p2x, p2y);  // t=11 writes 0s at m=150,151
    }

    float pv[5] = {0.f, 0.f, 0.f, 0.f, 0.f};
    for (int mq = 0; mq < 38; ++mq) {
      float4 vv = *(const float4*)&ar[BVB + t * 156 + 4 * mq];
#pragma unroll
      for (int i = 0; i < 5; ++i) {
        float4 pp = *(const float4*)&ar[rbase + i * 152 + 4 * mq];
        pv[i] += pp.x * vv.x + pp.y * vv.y + pp.z * vv.z + pp.w * vv.w;
      }
    }
#pragma unroll
    for (int i = 0; i < 5; ++i) ms += pv[i] * inv[i];
  }

  ar[BPART + g * 32 + t] = cfp + ms;
  __syncthreads();

  // ---- epilogue: mean over l, project with wo ----
  if (tid < 32) {
    float tot = 0.f;
#pragma unroll
    for (int gg = 0; gg < 8; ++gg) tot += ar[BPART + gg * 32 + tid];
    ar[BMS + tid] = tot * (1.f / 75.f);
  }
  __syncthreads();
  if (tid < 2) {
    float e = 0.f;
#pragma unroll
    for (int c2 = 0; c2 < CC; ++c2) e += wo[tid * CC + c2] * ar[BMS + c2];
    eout[a * 2 + tid] = e;
  }
}

// ---------------------------------------------------------------------------
// K5: meta head per site (unchanged)
// ---------------------------------------------------------------------------
__global__ __launch_bounds__(64) void k_meta(const float* __restrict__ cfs0,
                                             const float* __restrict__ cfa2,
                                             const float* __restrict__ mw,
                                             const float* __restrict__ mb,
                                             float* __restrict__ mout) {
  __shared__ float feat[64];
  __shared__ float lgt[3];
  const int s = blockIdx.x;
  const int tid = threadIdx.x;
  float f = 0.f;
  if (tid < 32) {
    const float* p = cfs0 + (size_t)s * (CC * LC) + tid * LC;
    for (int l = 0; l < LC; ++l) f += p[l];
  } else {
    const float* p0 = cfa2 + (size_t)(2 * s) * (CC * LC) + (tid - 32) * LC;
    const float* p1 = cfa2 + (size_t)(2 * s + 1) * (CC * LC) + (tid - 32) * LC;
    for (int l = 0; l < LC; ++l) f += p0[l] + p1[l];
  }
  feat[tid] = f * (1.f / 75.f);
  __syncthreads();
  if (tid < 3) {
    float acc2 = mb[tid];
    for (int c2 = 0; c2 < 64; ++c2) acc2 += mw[tid * 64 + c2] * feat[c2];
    lgt[tid] = acc2;
  }
  __syncthreads();
  if (tid < 3) {
    float mx = fmaxf(lgt[0], fmaxf(lgt[1], lgt[2]));
    float e0 = __expf(lgt[0] - mx), e1 = __expf(lgt[1] - mx), e2 = __expf(lgt[2] - mx);
    mout[s * 3 + tid] = __expf(lgt[tid] - mx) / (e0 + e1 + e2);
  }
}

// ---------------------------------------------------------------------------
extern "C" void kernel_launch(void* const* d_in, const int* in_sizes, int n_in,
                              void* d_out, int out_size, void* d_ws, size_t ws_size,
                              hipStream_t stream) {
  const float* t0      = (const float*)d_in[0];
  const float* t1      = (const float*)d_in[1];
  const float* conv0_w = (const float*)d_in[2];
  const float* conv1_w = (const float*)d_in[3];
  const float* comp0_w = (const float*)d_in[4];
  const float* comp1_w = (const float*)d_in[5];
  const float* comp2_w = (const float*)d_in[6];
  const float* xq0 = (const float*)d_in[7];
  const float* xk0 = (const float*)d_in[8];
  const float* xv0 = (const float*)d_in[9];
  const float* xo0 = (const float*)d_in[10];
  const float* xq1 = (const float*)d_in[11];
  const float* xk1 = (const float*)d_in[12];
  const float* xv1 = (const float*)d_in[13];
  const float* xo1 = (const float*)d_in[14];
  const float* xq2 = (const float*)d_in[15];
  const float* xk2 = (const float*)d_in[16];
  const float* xv2 = (const float*)d_in[17];
  const float* xo2 = (const float*)d_in[18];
  const float* comb_w = (const float*)d_in[19];
  const float* meta_w = (const float*)d_in[20];
  const float* meta_b = (const float*)d_in[21];

  float* wsf  = (float*)d_ws;
  float* red0 = wsf;
  float* red1 = red0 + (size_t)NA * CC * LL;
  float* cfa  = red1 + (size_t)NA * CC * LL;
  float* cfs0 = cfa + (size_t)NA * CC * LC;
  float* out  = (float*)d_out;

  k_conv_sum_mfma<<<NA, 256, 0, stream>>>(t0, conv0_w, red0);
  k_conv_sum_mfma<<<NA, 256, 0, stream>>>(t1, conv1_w, red1);

  k_compress<<<NA, 256, 0, stream>>>(red0, comp0_w, cfa, 0);
  k_compress<<<NS, 256, 0, stream>>>(red0, comp0_w, cfs0, 1);
  k_attn<<<NA, 256, 0, stream>>>(cfa, cfs0, xq0, xk0, xv0, xo0, out + 0);

  k_compress<<<NA, 256, 0, stream>>>(red1, comp1_w, cfa, 0);
  k_compress<<<NS, 256, 0, stream>>>(red1, comp1_w, cfs0, 1);
  k_attn<<<NA, 256, 0, stream>>>(cfa, cfs0, xq1, xk1, xv1, xo1, out + 2 * NA);

  k_comb<<<NA, 256, 0, stream>>>(red0, red1, comb_w, red0);
  k_compress<<<NA, 256, 0, stream>>>(red0, comp2_w, cfa, 0);
  k_compress<<<NS, 256, 0, stream>>>(red0, comp2_w, cfs0, 1);
  k_attn<<<NA, 256, 0, stream>>>(cfa, cfs0, xq2, xk2, xv2, xo2, out + 4 * NA);

  k_meta<<<NS, 64, 0, stream>>>(cfs0, cfa, meta_w, meta_b, out + 6 * NA);
}